// Round 1
// 161.464 us; speedup vs baseline: 1.0082x; 1.0082x over previous
//
#include <hip/hip_runtime.h>
#include <hip/hip_fp16.h>

// GCN 2-layer + classifier, fp32 math, fp16 message buffers.
// R9: gemm1 fused into hist kernel (6 launches). P1 is now UNSCALED h=X@W1;
//     source-side norm moved into aggF1 as gathered weight wk=inv[src]
//     (FMA already multiplies by wk -> free ALU, breaks gemm->CSR dependency).
// R9: agg loops use per-quarter bounds (j<e per lane) instead of wave-max dmax:
//     exec mask kills dead chunks -> ~25% fewer issued gather instrs.
// CSR-by-dst rebuilt per launch via radix partition, ZERO global atomics
// (R3: coarse global cursors serialize; R6: random scatter = 55MB dirty-line episodes).
//   k_histgemm: per-(tile,bucket) LDS histogram -> H[tile][bucket]  (+ fused W1 GEMM blocks)
//   k_scanH: per-bucket exclusive scan of H across tiles + bucket totals
//   k_scatA: recompute bucket bases via local LDS scan of btot, re-read tile,
//            write 4B rec (dloc<<16|src) at base+tileoff+LDS-rank
//   k_binB:  block per bucket: LDS node histogram+scan -> row_ptr/inv; u16 col coalesced
// k_aggF1: agg layer1 (inv[src]-weighted) + FUSED W2 GEMM (LDS rows, pad 65) -> P2 fp16
//          (P2 IS pre-scaled by inv: available by then -> aggF2 stays weight-free)
// k_aggF2: agg layer2 + fused classifier (transposed LDS Wc; R5: bank conflicts).
// Requires n < 65536 (u16 col). Here n=50000, E=800000.

#define FDIM 64
#define NCLS 16
#define TILE 2048

// ---- partition pass 1: per-(tile,bucket) histogram + fused layer-1 GEMM ----
// blocks [0, nblk): histogram tiles. blocks [nblk, nblk+nbG): Yh = fp16(X@W) rows.
__global__ __launch_bounds__(256) void k_histgemm(const int* __restrict__ dst, int E,
                                                  int* __restrict__ H, int nblk,
                                                  const float* __restrict__ X,
                                                  const float* __restrict__ W,
                                                  __half* __restrict__ Yh, int n) {
    __shared__ float Ws[FDIM * FDIM];
    __shared__ int h[256];
    int t = threadIdx.x, blk = blockIdx.x;
    if (blk < nblk) {
        h[t] = 0;
        __syncthreads();
        int i0 = blk * TILE;
#pragma unroll
        for (int k = 0; k < TILE / 256; ++k) {
            int i = i0 + k * 256 + t;
            if (i < E) atomicAdd(&h[dst[i] >> 8], 1);
        }
        __syncthreads();
        H[blk * 256 + t] = h[t];   // coalesced
    } else {
        for (int i = t; i < FDIM * FDIM; i += 256) Ws[i] = W[i];
        __syncthreads();
        int idx = (blk - nblk) * 256 + t;
        int row = idx >> 2;
        int cg = (idx & 3) * 16;
        if (row >= n) return;
        const float4* xr = (const float4*)(X + (size_t)row * FDIM);
        float4 xv[16];
#pragma unroll
        for (int i = 0; i < 16; ++i) xv[i] = xr[i];
        float acc[16];
#pragma unroll
        for (int c = 0; c < 16; ++c) acc[c] = 0.f;
#pragma unroll
        for (int i = 0; i < 16; ++i) {
            float xs[4] = {xv[i].x, xv[i].y, xv[i].z, xv[i].w};
#pragma unroll
            for (int j = 0; j < 4; ++j) {
                float xk = xs[j];
                const float* wr = &Ws[(i * 4 + j) * FDIM + cg];
#pragma unroll
                for (int c = 0; c < 16; ++c) acc[c] += xk * wr[c];
            }
        }
        unsigned u[8];
#pragma unroll
        for (int i = 0; i < 8; ++i) {
            __half2 hp = __floats2half2_rn(acc[2 * i], acc[2 * i + 1]);
            u[i] = *(unsigned*)&hp;
        }
        uint4* yo = (uint4*)(Yh + (size_t)row * FDIM + cg);
        yo[0] = make_uint4(u[0], u[1], u[2], u[3]);
        yo[1] = make_uint4(u[4], u[5], u[6], u[7]);
    }
}

// ---- partition pass 2: per-bucket exclusive scan across tiles ----
__global__ __launch_bounds__(512) void k_scanH(int* __restrict__ H, int nblk, int* __restrict__ btot) {
    __shared__ int s[512];
    int t = threadIdx.x, b = blockIdx.x;
    int v = (t < nblk) ? H[t * 256 + b] : 0;
    s[t] = v;
    __syncthreads();
    for (int off = 1; off < 512; off <<= 1) {
        int add = (t >= off) ? s[t - off] : 0;
        __syncthreads();
        s[t] += add;
        __syncthreads();
    }
    if (t < nblk) H[t * 256 + b] = s[t] - v;  // exclusive within bucket
    if (t == 511) btot[b] = s[511];
}

// ---- partition pass 3: scatter packed records into bucket regions ----
// bucket bases recomputed locally (identical deterministic scan in every block)
__global__ __launch_bounds__(256) void k_scatA(const int* __restrict__ src, const int* __restrict__ dst,
                                               int E, const int* __restrict__ H,
                                               const int* __restrict__ btot, int nb,
                                               unsigned* __restrict__ tmp) {
    __shared__ int s[256];
    __shared__ int Hb[256];
    __shared__ int c2[256];
    int t = threadIdx.x, blk = blockIdx.x;
    int v = (t < nb) ? btot[t] : 0;
    s[t] = v;
    __syncthreads();
    for (int off = 1; off < 256; off <<= 1) {
        int add = (t >= off) ? s[t - off] : 0;
        __syncthreads();
        s[t] += add;
        __syncthreads();
    }
    Hb[t] = (s[t] - v) + H[blk * 256 + t];   // bucket base + tile offset
    c2[t] = 0;
    __syncthreads();
    int i0 = blk * TILE;
#pragma unroll
    for (int k = 0; k < TILE / 256; ++k) {
        int i = i0 + k * 256 + t;
        if (i < E) {
            int sv = src[i], d = dst[i];
            int b = d >> 8;
            unsigned rec = ((unsigned)(d & 255) << 16) | (unsigned)sv;
            int pos = Hb[b] + atomicAdd(&c2[b], 1);
            tmp[pos] = rec;
        }
    }
}

// ---- per-bucket CSR finalize: row_ptr, inv, coalesced u16 col ----
#define COLCAP 8192
__global__ __launch_bounds__(256) void k_binB(const unsigned* __restrict__ tmp,
                                              const int* __restrict__ btot, int nb,
                                              int n, int E, int* __restrict__ row_ptr,
                                              float* __restrict__ inv,
                                              unsigned short* __restrict__ col) {
    __shared__ int dcnt[256], s[256], cur[256];
    __shared__ unsigned short colbuf[COLCAP];
    int t = threadIdx.x, b = blockIdx.x;
    // local scan of btot -> this bucket's base
    int v = (t < nb) ? btot[t] : 0;
    s[t] = v;
    __syncthreads();
    for (int off = 1; off < 256; off <<= 1) {
        int add = (t >= off) ? s[t - off] : 0;
        __syncthreads();
        s[t] += add;
        __syncthreads();
    }
    __shared__ int baseS;
    if (t == b) baseS = s[t] - v;
    dcnt[t] = 0;
    __syncthreads();
    int base = baseS;
    int cntE = btot[b];
    int node0 = b << 8;
    int nn = min(256, n - node0);
    for (int i = t; i < cntE; i += 256) atomicAdd(&dcnt[tmp[base + i] >> 16], 1);
    __syncthreads();
    int deg = dcnt[t];
    s[t] = deg;
    __syncthreads();
    for (int off = 1; off < 256; off <<= 1) {
        int add = (t >= off) ? s[t - off] : 0;
        __syncthreads();
        s[t] += add;
        __syncthreads();
    }
    int excl = s[t] - deg;
    if (t < nn) {
        row_ptr[node0 + t] = base + excl;
        inv[node0 + t] = rsqrtf((float)(deg + 1));
    }
    if (b == 0 && t == 0) row_ptr[n] = E;
    cur[t] = excl;
    __syncthreads();
    for (int i = t; i < cntE; i += 256) {
        unsigned r = tmp[base + i];
        int pos = atomicAdd(&cur[r >> 16], 1);
        unsigned short vv = (unsigned short)(r & 0xFFFFu);
        if (pos < COLCAP) colbuf[pos] = vv;
        else col[base + pos] = vv;   // overflow fallback (never expected at E/n=16)
    }
    __syncthreads();
    int lim = min(cntE, COLCAP);
    for (int i = t; i < lim; i += 256) col[base + i] = colbuf[i];
}

// ---- agg layer 1 (inv[src]-weighted) + fused W2 GEMM -> P2 (fp16) ----
// Phase A: 4 nodes/wave, 16 lanes x 4 halfs/row; per-quarter loop bounds
// (exec mask retires finished quarters -> no dead-chunk loads);
// wk = inv[src] gathered (P1 unscaled). Staged to rbuf[16][65].
// Phase B: thread=(node,cg): P2[node][cg*4..+3] = fp16(inv * (r @ W2)[cg*4..+3])
__global__ __launch_bounds__(256) void k_aggF1(const __half* __restrict__ Ph, const float* __restrict__ inv,
                                               const int* __restrict__ row_ptr,
                                               const unsigned short* __restrict__ col,
                                               const float* __restrict__ bias,
                                               const float* __restrict__ W2,
                                               __half* __restrict__ P2, int n) {
    __shared__ float W2s[FDIM * FDIM];
    __shared__ float rbuf[16][FDIM + 1];
    int t = threadIdx.x;
    for (int i = t; i < FDIM * FDIM; i += 256) W2s[i] = W2[i];
    int lane = t & 63;
    int sub = lane >> 4;
    int fl = lane & 15;
    int wid = t >> 6;
    int nl = wid * 4 + sub;                 // local node 0..15
    int node = blockIdx.x * 16 + nl;
    bool alive = node < n;
    int nodeC = alive ? node : (n - 1);
    float iv = inv[nodeC];
    const uint2* Pq = (const uint2*)Ph;
    uint2 selfq = Pq[(size_t)nodeC * 16 + fl];
    float2 sf0 = __half22float2(*(__half2*)&selfq.x);
    float2 sf1 = __half22float2(*(__half2*)&selfq.y);
    // self term: inv[d] * h[d]  (P1 unscaled now)
    float4 acc = make_float4(iv * sf0.x, iv * sf0.y, iv * sf1.x, iv * sf1.y);
    int s = row_ptr[nodeC];
    int e = alive ? row_ptr[nodeC + 1] : s;
    for (int j = s; j < e; j += 8) {
        int c[8];
        float wk[8];
        uint2 q[8];
#pragma unroll
        for (int k = 0; k < 8; ++k) {
            int jj = j + k;
            bool ok = jj < e;
            c[k] = col[ok ? jj : s];
        }
#pragma unroll
        for (int k = 0; k < 8; ++k) wk[k] = ((j + k) < e) ? inv[c[k]] : 0.f;
#pragma unroll
        for (int k = 0; k < 8; ++k) q[k] = Pq[(size_t)c[k] * 16 + fl];
#pragma unroll
        for (int k = 0; k < 8; ++k) {
            float2 f0 = __half22float2(*(__half2*)&q[k].x);
            float2 f1 = __half22float2(*(__half2*)&q[k].y);
            acc.x = fmaf(wk[k], f0.x, acc.x);
            acc.y = fmaf(wk[k], f0.y, acc.y);
            acc.z = fmaf(wk[k], f1.x, acc.z);
            acc.w = fmaf(wk[k], f1.y, acc.w);
        }
    }
    float4 bb = ((const float4*)bias)[fl];
    rbuf[nl][fl * 4 + 0] = fmaxf(fmaf(iv, acc.x, bb.x), 0.f);
    rbuf[nl][fl * 4 + 1] = fmaxf(fmaf(iv, acc.y, bb.y), 0.f);
    rbuf[nl][fl * 4 + 2] = fmaxf(fmaf(iv, acc.z, bb.z), 0.f);
    rbuf[nl][fl * 4 + 3] = fmaxf(fmaf(iv, acc.w, bb.w), 0.f);
    __syncthreads();   // covers W2s load too
    // Phase B: 256 threads = 16 nodes x 16 col-groups
    int nl2 = t >> 4;
    int cg = t & 15;
    int node2 = blockIdx.x * 16 + nl2;
    const float* rr = rbuf[nl2];
    float a0 = 0.f, a1 = 0.f, a2 = 0.f, a3 = 0.f;
#pragma unroll
    for (int i = 0; i < FDIM; ++i) {
        float xk = rr[i];
        const float* wv = &W2s[i * FDIM + cg * 4];
        a0 = fmaf(xk, wv[0], a0);
        a1 = fmaf(xk, wv[1], a1);
        a2 = fmaf(xk, wv[2], a2);
        a3 = fmaf(xk, wv[3], a3);
    }
    if (node2 < n) {
        float iv2 = inv[node2];
        __half2 h0 = __floats2half2_rn(a0 * iv2, a1 * iv2);
        __half2 h1 = __floats2half2_rn(a2 * iv2, a3 * iv2);
        uint2 val = make_uint2(*(unsigned*)&h0, *(unsigned*)&h1);
        ((uint2*)P2)[(size_t)node2 * 16 + cg] = val;
    }
}

// ---- agg layer 2 + fused classifier (P2 pre-scaled -> weight-free) ----
__global__ __launch_bounds__(256) void k_aggF2(const __half* __restrict__ Ph, const float* __restrict__ inv,
                                               const int* __restrict__ row_ptr,
                                               const unsigned short* __restrict__ col,
                                               const float* __restrict__ bias,
                                               const float* __restrict__ Wc, const float* __restrict__ bc,
                                               float* __restrict__ out, int n) {
    __shared__ float WcT[NCLS * FDIM];   // transposed: WcT[c*64+f]
    int t = threadIdx.x;
    for (int i = t; i < FDIM * NCLS; i += 256) {
        int c = i & 15, f = i >> 4;
        WcT[c * FDIM + f] = Wc[i];
    }
    __syncthreads();
    int lane = t & 63;
    int sub = lane >> 4;
    int fl = lane & 15;
    int wid = t >> 6;
    int node = blockIdx.x * 16 + wid * 4 + sub;
    bool alive = node < n;
    int nodeC = alive ? node : (n - 1);
    float iv = inv[nodeC];
    const uint2* Pq = (const uint2*)Ph;
    uint2 selfq = Pq[(size_t)nodeC * 16 + fl];
    float2 sf0 = __half22float2(*(__half2*)&selfq.x);
    float2 sf1 = __half22float2(*(__half2*)&selfq.y);
    float4 acc = make_float4(sf0.x, sf0.y, sf1.x, sf1.y);
    int s = row_ptr[nodeC];
    int e = alive ? row_ptr[nodeC + 1] : s;
    for (int j = s; j < e; j += 8) {
        int c[8];
        float wk[8];
        uint2 q[8];
#pragma unroll
        for (int k = 0; k < 8; ++k) {
            int jj = j + k;
            bool ok = jj < e;
            c[k] = col[ok ? jj : s];
            wk[k] = ok ? 1.f : 0.f;
        }
#pragma unroll
        for (int k = 0; k < 8; ++k) q[k] = Pq[(size_t)c[k] * 16 + fl];
#pragma unroll
        for (int k = 0; k < 8; ++k) {
            float2 f0 = __half22float2(*(__half2*)&q[k].x);
            float2 f1 = __half22float2(*(__half2*)&q[k].y);
            acc.x = fmaf(wk[k], f0.x, acc.x);
            acc.y = fmaf(wk[k], f0.y, acc.y);
            acc.z = fmaf(wk[k], f1.x, acc.z);
            acc.w = fmaf(wk[k], f1.y, acc.w);
        }
    }
    float4 bb = ((const float4*)bias)[fl];
    float4 r;
    r.x = fmaxf(fmaf(iv, acc.x, bb.x), 0.f);
    r.y = fmaxf(fmaf(iv, acc.y, bb.y), 0.f);
    r.z = fmaxf(fmaf(iv, acc.z, bb.z), 0.f);
    r.w = fmaxf(fmaf(iv, acc.w, bb.w), 0.f);
    float part[NCLS];
#pragma unroll
    for (int c = 0; c < NCLS; ++c) {
        float4 wv = ((const float4*)(WcT + c * FDIM))[fl];
        part[c] = fmaf(r.x, wv.x, fmaf(r.y, wv.y, fmaf(r.z, wv.z, r.w * wv.w)));
    }
#pragma unroll
    for (int m = 1; m < 16; m <<= 1) {
#pragma unroll
        for (int c = 0; c < NCLS; ++c) part[c] += __shfl_xor(part[c], m, 64);
    }
    if (alive && fl < 4) {
        float4 bb2 = ((const float4*)bc)[fl];
        float4 o = make_float4(part[fl * 4 + 0] + bb2.x, part[fl * 4 + 1] + bb2.y,
                               part[fl * 4 + 2] + bb2.z, part[fl * 4 + 3] + bb2.w);
        ((float4*)out)[(size_t)node * 4 + fl] = o;
    }
}

static inline size_t align256(size_t x) { return (x + 255) & ~(size_t)255; }

extern "C" void kernel_launch(void* const* d_in, const int* in_sizes, int n_in,
                              void* d_out, int out_size, void* d_ws, size_t ws_size,
                              hipStream_t stream) {
    const float* x  = (const float*)d_in[0];
    const int*   ei = (const int*)d_in[1];
    const float* W1 = (const float*)d_in[2];
    const float* b1 = (const float*)d_in[3];
    const float* W2 = (const float*)d_in[4];
    const float* b2 = (const float*)d_in[5];
    const float* Wc = (const float*)d_in[6];
    const float* bc = (const float*)d_in[7];
    float* out = (float*)d_out;

    const int n = in_sizes[0] / FDIM;   // 50000
    const int E = in_sizes[1] / 2;      // 800000
    const int* src = ei;
    const int* dst = ei + E;

    const int nb = (n + 255) >> 8;            // 196 buckets
    const int nblk = (E + TILE - 1) / TILE;   // 391 tiles

    // workspace carve-up
    char* w = (char*)d_ws;
    size_t off = 0;
    int* H = (int*)(w + off);        off = align256(off + (size_t)nblk * 256 * 4);
    int* btot = (int*)(w + off);     off = align256(off + 256 * 4);
    int* row_ptr = (int*)(w + off);  off = align256(off + (size_t)(n + 1) * 4);
    float* inv = (float*)(w + off);  off = align256(off + (size_t)n * 4);
    unsigned* tmp = (unsigned*)(w + off);             off = align256(off + (size_t)E * 4);
    unsigned short* col = (unsigned short*)(w + off); off = align256(off + (size_t)(E + 8) * 2);
    __half* P1 = (__half*)(w + off); off = align256(off + (size_t)n * FDIM * 2);
    __half* P2 = (__half*)(w + off); off = align256(off + (size_t)n * FDIM * 2);
    (void)ws_size;

    const int nbG = (n * 4 + 255) / 256;
    const int nbA = (n + 15) / 16;     // 16 nodes per block

    // CSR build + fused layer-1 GEMM riding along (gemm no longer needs inv)
    k_histgemm<<<nblk + nbG, 256, 0, stream>>>(dst, E, H, nblk, x, W1, P1, n);
    k_scanH<<<nb, 512, 0, stream>>>(H, nblk, btot);
    k_scatA<<<nblk, 256, 0, stream>>>(src, dst, E, H, btot, nb, tmp);
    k_binB<<<nb, 256, 0, stream>>>(tmp, btot, nb, n, E, row_ptr, inv, col);

    // layer 1 agg (inv[src]-weighted) + fused layer 2 GEMM -> P2 (pre-scaled)
    k_aggF1<<<nbA, 256, 0, stream>>>(P1, inv, row_ptr, col, b1, W2, P2, n);
    // layer 2 agg + fused classifier
    k_aggF2<<<nbA, 256, 0, stream>>>(P2, inv, row_ptr, col, b2, Wc, bc, out, n);
}

// Round 2
// 156.774 us; speedup vs baseline: 1.0383x; 1.0299x over previous
//
#include <hip/hip_runtime.h>
#include <hip/hip_fp16.h>

// GCN 2-layer + classifier, fp32 math, fp16 message buffers.
// R10: agg kernels restructured 16lanes/node*uint2 -> 8lanes/node*uint4:
//      one wave covers 8 nodes (was 4); per 8-edge chunk the same 24 VMEM
//      instructions now cover 64 edges (was 32) -> gather/col/inv issue
//      count per edge HALVES. Aggs are issue-bound (R9 post-mortem: per-lane
//      bounds saved bandwidth only -> neutral; avg pipeline BW 0.9 TB/s << roof).
// R9: gemm1 fused into hist kernel (6 launches). P1 UNSCALED h=X@W1;
//     source-side norm applied in aggF1 as gathered weight wk=inv[src].
// CSR-by-dst rebuilt per launch via radix partition, ZERO global atomics
// (R3: coarse global cursors serialize; R6: random scatter = 55MB dirty-line episodes).
//   k_histgemm: per-(tile,bucket) LDS histogram -> H[tile][bucket] (+ fused W1 GEMM blocks)
//   k_scanH: per-bucket exclusive scan of H across tiles + bucket totals
//   k_scatA: recompute bucket bases via local LDS scan of btot, re-read tile,
//            write 4B rec (dloc<<16|src) at base+tileoff+LDS-rank
//   k_binB:  block per bucket: LDS node histogram+scan -> row_ptr/inv; u16 col coalesced
// k_aggF1: agg layer1 (inv[src]-weighted) + FUSED W2 GEMM (LDS rows, pad 65) -> P2 fp16
//          (P2 pre-scaled by inv -> aggF2 stays weight-free)
// k_aggF2: agg layer2 + fused classifier (transposed LDS Wc).
// Requires n < 65536 (u16 col). Here n=50000, E=800000.

#define FDIM 64
#define NCLS 16
#define TILE 2048

// ---- partition pass 1: per-(tile,bucket) histogram + fused layer-1 GEMM ----
__global__ __launch_bounds__(256) void k_histgemm(const int* __restrict__ dst, int E,
                                                  int* __restrict__ H, int nblk,
                                                  const float* __restrict__ X,
                                                  const float* __restrict__ W,
                                                  __half* __restrict__ Yh, int n) {
    __shared__ float Ws[FDIM * FDIM];
    __shared__ int h[256];
    int t = threadIdx.x, blk = blockIdx.x;
    if (blk < nblk) {
        h[t] = 0;
        __syncthreads();
        int i0 = blk * TILE;
#pragma unroll
        for (int k = 0; k < TILE / 256; ++k) {
            int i = i0 + k * 256 + t;
            if (i < E) atomicAdd(&h[dst[i] >> 8], 1);
        }
        __syncthreads();
        H[blk * 256 + t] = h[t];   // coalesced
    } else {
        for (int i = t; i < FDIM * FDIM; i += 256) Ws[i] = W[i];
        __syncthreads();
        int idx = (blk - nblk) * 256 + t;
        int row = idx >> 2;
        int cg = (idx & 3) * 16;
        if (row >= n) return;
        const float4* xr = (const float4*)(X + (size_t)row * FDIM);
        float4 xv[16];
#pragma unroll
        for (int i = 0; i < 16; ++i) xv[i] = xr[i];
        float acc[16];
#pragma unroll
        for (int c = 0; c < 16; ++c) acc[c] = 0.f;
#pragma unroll
        for (int i = 0; i < 16; ++i) {
            float xs[4] = {xv[i].x, xv[i].y, xv[i].z, xv[i].w};
#pragma unroll
            for (int j = 0; j < 4; ++j) {
                float xk = xs[j];
                const float* wr = &Ws[(i * 4 + j) * FDIM + cg];
#pragma unroll
                for (int c = 0; c < 16; ++c) acc[c] += xk * wr[c];
            }
        }
        unsigned u[8];
#pragma unroll
        for (int i = 0; i < 8; ++i) {
            __half2 hp = __floats2half2_rn(acc[2 * i], acc[2 * i + 1]);
            u[i] = *(unsigned*)&hp;
        }
        uint4* yo = (uint4*)(Yh + (size_t)row * FDIM + cg);
        yo[0] = make_uint4(u[0], u[1], u[2], u[3]);
        yo[1] = make_uint4(u[4], u[5], u[6], u[7]);
    }
}

// ---- partition pass 2: per-bucket exclusive scan across tiles ----
__global__ __launch_bounds__(512) void k_scanH(int* __restrict__ H, int nblk, int* __restrict__ btot) {
    __shared__ int s[512];
    int t = threadIdx.x, b = blockIdx.x;
    int v = (t < nblk) ? H[t * 256 + b] : 0;
    s[t] = v;
    __syncthreads();
    for (int off = 1; off < 512; off <<= 1) {
        int add = (t >= off) ? s[t - off] : 0;
        __syncthreads();
        s[t] += add;
        __syncthreads();
    }
    if (t < nblk) H[t * 256 + b] = s[t] - v;  // exclusive within bucket
    if (t == 511) btot[b] = s[511];
}

// ---- partition pass 3: scatter packed records into bucket regions ----
__global__ __launch_bounds__(256) void k_scatA(const int* __restrict__ src, const int* __restrict__ dst,
                                               int E, const int* __restrict__ H,
                                               const int* __restrict__ btot, int nb,
                                               unsigned* __restrict__ tmp) {
    __shared__ int s[256];
    __shared__ int Hb[256];
    __shared__ int c2[256];
    int t = threadIdx.x, blk = blockIdx.x;
    int v = (t < nb) ? btot[t] : 0;
    s[t] = v;
    __syncthreads();
    for (int off = 1; off < 256; off <<= 1) {
        int add = (t >= off) ? s[t - off] : 0;
        __syncthreads();
        s[t] += add;
        __syncthreads();
    }
    Hb[t] = (s[t] - v) + H[blk * 256 + t];   // bucket base + tile offset
    c2[t] = 0;
    __syncthreads();
    int i0 = blk * TILE;
#pragma unroll
    for (int k = 0; k < TILE / 256; ++k) {
        int i = i0 + k * 256 + t;
        if (i < E) {
            int sv = src[i], d = dst[i];
            int b = d >> 8;
            unsigned rec = ((unsigned)(d & 255) << 16) | (unsigned)sv;
            int pos = Hb[b] + atomicAdd(&c2[b], 1);
            tmp[pos] = rec;
        }
    }
}

// ---- per-bucket CSR finalize: row_ptr, inv, coalesced u16 col ----
#define COLCAP 8192
__global__ __launch_bounds__(256) void k_binB(const unsigned* __restrict__ tmp,
                                              const int* __restrict__ btot, int nb,
                                              int n, int E, int* __restrict__ row_ptr,
                                              float* __restrict__ inv,
                                              unsigned short* __restrict__ col) {
    __shared__ int dcnt[256], s[256], cur[256];
    __shared__ unsigned short colbuf[COLCAP];
    int t = threadIdx.x, b = blockIdx.x;
    int v = (t < nb) ? btot[t] : 0;
    s[t] = v;
    __syncthreads();
    for (int off = 1; off < 256; off <<= 1) {
        int add = (t >= off) ? s[t - off] : 0;
        __syncthreads();
        s[t] += add;
        __syncthreads();
    }
    __shared__ int baseS;
    if (t == b) baseS = s[t] - v;
    dcnt[t] = 0;
    __syncthreads();
    int base = baseS;
    int cntE = btot[b];
    int node0 = b << 8;
    int nn = min(256, n - node0);
    for (int i = t; i < cntE; i += 256) atomicAdd(&dcnt[tmp[base + i] >> 16], 1);
    __syncthreads();
    int deg = dcnt[t];
    s[t] = deg;
    __syncthreads();
    for (int off = 1; off < 256; off <<= 1) {
        int add = (t >= off) ? s[t - off] : 0;
        __syncthreads();
        s[t] += add;
        __syncthreads();
    }
    int excl = s[t] - deg;
    if (t < nn) {
        row_ptr[node0 + t] = base + excl;
        inv[node0 + t] = rsqrtf((float)(deg + 1));
    }
    if (b == 0 && t == 0) row_ptr[n] = E;
    cur[t] = excl;
    __syncthreads();
    for (int i = t; i < cntE; i += 256) {
        unsigned r = tmp[base + i];
        int pos = atomicAdd(&cur[r >> 16], 1);
        unsigned short vv = (unsigned short)(r & 0xFFFFu);
        if (pos < COLCAP) colbuf[pos] = vv;
        else col[base + pos] = vv;   // overflow fallback
    }
    __syncthreads();
    int lim = min(cntE, COLCAP);
    for (int i = t; i < lim; i += 256) col[base + i] = colbuf[i];
}

__device__ __forceinline__ void unpack8(const uint4& q, float* f) {
    float2 f0 = __half22float2(*(const __half2*)&q.x);
    float2 f1 = __half22float2(*(const __half2*)&q.y);
    float2 f2 = __half22float2(*(const __half2*)&q.z);
    float2 f3 = __half22float2(*(const __half2*)&q.w);
    f[0] = f0.x; f[1] = f0.y; f[2] = f1.x; f[3] = f1.y;
    f[4] = f2.x; f[5] = f2.y; f[6] = f3.x; f[7] = f3.y;
}

// ---- agg layer 1 (inv[src]-weighted) + fused W2 GEMM -> P2 (fp16) ----
// Phase A: 8 nodes/wave, 8 lanes x 8 halfs (uint4); 32 nodes/block.
// Phase B: 256 threads = 32 nodes x 8 col-octets; P2 = fp16(inv * (r @ W2)).
__global__ __launch_bounds__(256) void k_aggF1(const __half* __restrict__ Ph, const float* __restrict__ inv,
                                               const int* __restrict__ row_ptr,
                                               const unsigned short* __restrict__ col,
                                               const float* __restrict__ bias,
                                               const float* __restrict__ W2,
                                               __half* __restrict__ P2, int n) {
    __shared__ float W2s[FDIM * FDIM];
    __shared__ float rbuf[32][FDIM + 1];
    int t = threadIdx.x;
    for (int i = t; i < FDIM * FDIM; i += 256) W2s[i] = W2[i];
    int lane = t & 63;
    int sub = lane >> 3;      // node-in-wave 0..7
    int fl = lane & 7;        // feature octet 0..7
    int wid = t >> 6;
    int nl = wid * 8 + sub;   // local node 0..31
    int node = blockIdx.x * 32 + nl;
    bool alive = node < n;
    int nodeC = alive ? node : (n - 1);
    float iv = inv[nodeC];
    const uint4* Pq = (const uint4*)Ph;
    uint4 selfq = Pq[(size_t)nodeC * 8 + fl];
    float a[8], f[8];
    unpack8(selfq, f);
#pragma unroll
    for (int i = 0; i < 8; ++i) a[i] = iv * f[i];   // self term: inv[d]*h[d]
    int s = row_ptr[nodeC];
    int e = alive ? row_ptr[nodeC + 1] : s;
    for (int j = s; j < e; j += 8) {
        int c[8];
        float wk[8];
        uint4 q[8];
#pragma unroll
        for (int k = 0; k < 8; ++k) {
            int jj = j + k;
            c[k] = col[jj < e ? jj : s];
        }
#pragma unroll
        for (int k = 0; k < 8; ++k) wk[k] = ((j + k) < e) ? inv[c[k]] : 0.f;
#pragma unroll
        for (int k = 0; k < 8; ++k) q[k] = Pq[(size_t)c[k] * 8 + fl];
#pragma unroll
        for (int k = 0; k < 8; ++k) {
            unpack8(q[k], f);
#pragma unroll
            for (int i = 0; i < 8; ++i) a[i] = fmaf(wk[k], f[i], a[i]);
        }
    }
    float4 bb0 = ((const float4*)bias)[fl * 2];
    float4 bb1 = ((const float4*)bias)[fl * 2 + 1];
    float bbv[8] = {bb0.x, bb0.y, bb0.z, bb0.w, bb1.x, bb1.y, bb1.z, bb1.w};
#pragma unroll
    for (int i = 0; i < 8; ++i)
        rbuf[nl][fl * 8 + i] = fmaxf(fmaf(iv, a[i], bbv[i]), 0.f);
    __syncthreads();   // covers W2s load too
    // Phase B: 256 threads = 32 nodes x 8 col-octets
    int nl2 = t >> 3;
    int cg = t & 7;
    int node2 = blockIdx.x * 32 + nl2;
    const float* rr = rbuf[nl2];
    float o[8];
#pragma unroll
    for (int i = 0; i < 8; ++i) o[i] = 0.f;
#pragma unroll
    for (int i = 0; i < FDIM; ++i) {
        float xk = rr[i];
        const float* wv = &W2s[i * FDIM + cg * 8];
#pragma unroll
        for (int c = 0; c < 8; ++c) o[c] = fmaf(xk, wv[c], o[c]);
    }
    if (node2 < n) {
        float iv2 = inv[node2];
        unsigned u[4];
#pragma unroll
        for (int i = 0; i < 4; ++i) {
            __half2 hp = __floats2half2_rn(o[2 * i] * iv2, o[2 * i + 1] * iv2);
            u[i] = *(unsigned*)&hp;
        }
        ((uint4*)P2)[(size_t)node2 * 8 + cg] = make_uint4(u[0], u[1], u[2], u[3]);
    }
}

// ---- agg layer 2 + fused classifier (P2 pre-scaled -> weight-free) ----
__global__ __launch_bounds__(256) void k_aggF2(const __half* __restrict__ Ph, const float* __restrict__ inv,
                                               const int* __restrict__ row_ptr,
                                               const unsigned short* __restrict__ col,
                                               const float* __restrict__ bias,
                                               const float* __restrict__ Wc, const float* __restrict__ bc,
                                               float* __restrict__ out, int n) {
    __shared__ float WcT[NCLS * FDIM];   // transposed: WcT[c*64+f]
    int t = threadIdx.x;
    for (int i = t; i < FDIM * NCLS; i += 256) {
        int c = i & 15, ff = i >> 4;
        WcT[c * FDIM + ff] = Wc[i];
    }
    __syncthreads();
    int lane = t & 63;
    int sub = lane >> 3;
    int fl = lane & 7;
    int wid = t >> 6;
    int node = blockIdx.x * 32 + wid * 8 + sub;
    bool alive = node < n;
    int nodeC = alive ? node : (n - 1);
    float iv = inv[nodeC];
    const uint4* Pq = (const uint4*)Ph;
    uint4 selfq = Pq[(size_t)nodeC * 8 + fl];
    float a[8], f[8];
    unpack8(selfq, a);
    int s = row_ptr[nodeC];
    int e = alive ? row_ptr[nodeC + 1] : s;
    for (int j = s; j < e; j += 8) {
        int c[8];
        float wk[8];
        uint4 q[8];
#pragma unroll
        for (int k = 0; k < 8; ++k) {
            int jj = j + k;
            c[k] = col[jj < e ? jj : s];
            wk[k] = (jj < e) ? 1.f : 0.f;
        }
#pragma unroll
        for (int k = 0; k < 8; ++k) q[k] = Pq[(size_t)c[k] * 8 + fl];
#pragma unroll
        for (int k = 0; k < 8; ++k) {
            unpack8(q[k], f);
#pragma unroll
            for (int i = 0; i < 8; ++i) a[i] = fmaf(wk[k], f[i], a[i]);
        }
    }
    float4 bb0 = ((const float4*)bias)[fl * 2];
    float4 bb1 = ((const float4*)bias)[fl * 2 + 1];
    float bbv[8] = {bb0.x, bb0.y, bb0.z, bb0.w, bb1.x, bb1.y, bb1.z, bb1.w};
    float r[8];
#pragma unroll
    for (int i = 0; i < 8; ++i) r[i] = fmaxf(fmaf(iv, a[i], bbv[i]), 0.f);
    float part[NCLS];
#pragma unroll
    for (int c = 0; c < NCLS; ++c) {
        float4 wv0 = ((const float4*)(WcT + c * FDIM))[fl * 2];
        float4 wv1 = ((const float4*)(WcT + c * FDIM))[fl * 2 + 1];
        part[c] = r[0] * wv0.x;
        part[c] = fmaf(r[1], wv0.y, part[c]);
        part[c] = fmaf(r[2], wv0.z, part[c]);
        part[c] = fmaf(r[3], wv0.w, part[c]);
        part[c] = fmaf(r[4], wv1.x, part[c]);
        part[c] = fmaf(r[5], wv1.y, part[c]);
        part[c] = fmaf(r[6], wv1.z, part[c]);
        part[c] = fmaf(r[7], wv1.w, part[c]);
    }
#pragma unroll
    for (int m = 1; m < 8; m <<= 1) {
#pragma unroll
        for (int c = 0; c < NCLS; ++c) part[c] += __shfl_xor(part[c], m, 64);
    }
    if (alive && fl < 4) {
        float4 bb2 = ((const float4*)bc)[fl];
        float4 o = make_float4(part[fl * 4 + 0] + bb2.x, part[fl * 4 + 1] + bb2.y,
                               part[fl * 4 + 2] + bb2.z, part[fl * 4 + 3] + bb2.w);
        ((float4*)out)[(size_t)node * 4 + fl] = o;
    }
}

static inline size_t align256(size_t x) { return (x + 255) & ~(size_t)255; }

extern "C" void kernel_launch(void* const* d_in, const int* in_sizes, int n_in,
                              void* d_out, int out_size, void* d_ws, size_t ws_size,
                              hipStream_t stream) {
    const float* x  = (const float*)d_in[0];
    const int*   ei = (const int*)d_in[1];
    const float* W1 = (const float*)d_in[2];
    const float* b1 = (const float*)d_in[3];
    const float* W2 = (const float*)d_in[4];
    const float* b2 = (const float*)d_in[5];
    const float* Wc = (const float*)d_in[6];
    const float* bc = (const float*)d_in[7];
    float* out = (float*)d_out;

    const int n = in_sizes[0] / FDIM;   // 50000
    const int E = in_sizes[1] / 2;      // 800000
    const int* src = ei;
    const int* dst = ei + E;

    const int nb = (n + 255) >> 8;            // 196 buckets
    const int nblk = (E + TILE - 1) / TILE;   // 391 tiles

    // workspace carve-up
    char* w = (char*)d_ws;
    size_t off = 0;
    int* H = (int*)(w + off);        off = align256(off + (size_t)nblk * 256 * 4);
    int* btot = (int*)(w + off);     off = align256(off + 256 * 4);
    int* row_ptr = (int*)(w + off);  off = align256(off + (size_t)(n + 1) * 4);
    float* inv = (float*)(w + off);  off = align256(off + (size_t)n * 4);
    unsigned* tmp = (unsigned*)(w + off);             off = align256(off + (size_t)E * 4);
    unsigned short* col = (unsigned short*)(w + off); off = align256(off + (size_t)(E + 8) * 2);
    __half* P1 = (__half*)(w + off); off = align256(off + (size_t)n * FDIM * 2);
    __half* P2 = (__half*)(w + off); off = align256(off + (size_t)n * FDIM * 2);
    (void)ws_size;

    const int nbG = (n * 4 + 255) / 256;
    const int nbA = (n + 31) / 32;     // 32 nodes per block

    // CSR build + fused layer-1 GEMM riding along
    k_histgemm<<<nblk + nbG, 256, 0, stream>>>(dst, E, H, nblk, x, W1, P1, n);
    k_scanH<<<nb, 512, 0, stream>>>(H, nblk, btot);
    k_scatA<<<nblk, 256, 0, stream>>>(src, dst, E, H, btot, nb, tmp);
    k_binB<<<nb, 256, 0, stream>>>(tmp, btot, nb, n, E, row_ptr, inv, col);

    // layer 1 agg (inv[src]-weighted) + fused layer 2 GEMM -> P2 (pre-scaled)
    k_aggF1<<<nbA, 256, 0, stream>>>(P1, inv, row_ptr, col, b1, W2, P2, n);
    // layer 2 agg + fused classifier
    k_aggF2<<<nbA, 256, 0, stream>>>(P2, inv, row_ptr, col, b2, Wc, bc, out, n);
}